// Round 1
// baseline (310.390 us; speedup 1.0000x reference)
//
#include <hip/hip_runtime.h>

#define NGRAPHS 64
#define DIM 480            // 480 floats per row
#define NCH 224            // 128 scalar + 64 vec3 + 32 vec5 channels
#define EPS 1e-5f
#define ROWS_PER_BLOCK 256

// ws layout (float slots):
// [0, 14336)            sumsq per (g, channel)           64*224
// [14336, 22528)        sum per (g, scalar channel)      64*128
// [22528, 53248)        A table per (g, col)             64*480
// [53248, 83968)        B table per (g, col)             64*480
// [83968, 84033)        start offsets (int)              65
#define OFF_SUMSQ 0
#define OFF_SUM   14336
#define OFF_A     22528
#define OFF_B     53248
#define OFF_START 83968
#define NZERO     22528   // floats to zero (sumsq + sum)

__device__ __forceinline__ int col2ch(int col) {
    if (col < 128) return col;
    if (col < 320) return 128 + (col - 128) / 3;
    return 192 + (col - 320) / 5;
}

__global__ __launch_bounds__(256) void zero_kernel(float* ws) {
    int i = blockIdx.x * 256 + threadIdx.x;
    if (i < NZERO) ws[i] = 0.0f;
}

__global__ void start_kernel(const int* __restrict__ bid, int* __restrict__ start, int N) {
    int g = threadIdx.x;
    if (g > NGRAPHS) return;
    // lower_bound: smallest i with bid[i] >= g
    int lo = 0, hi = N;
    while (lo < hi) {
        int mid = (lo + hi) >> 1;
        if (bid[mid] < g) lo = mid + 1; else hi = mid;
    }
    start[g] = lo;
}

__device__ __forceinline__ void flush_stats(float* __restrict__ ws, int g, int tx,
                                            float (&ssq)[8], float (&ssum)[4]) {
    float* sq = ws + OFF_SUMSQ + (size_t)g * NCH;
    float* sm = ws + OFF_SUM   + (size_t)g * 128;
#pragma unroll
    for (int j = 0; j < 4; ++j) {
        int col = 4 * tx + j;            // cols 0..255
        atomicAdd(&sq[col2ch(col)], ssq[j]);
        ssq[j] = 0.0f;
        if (col < 128) { atomicAdd(&sm[col], ssum[j]); ssum[j] = 0.0f; }
    }
    if (tx < 56) {
#pragma unroll
        for (int j = 0; j < 4; ++j) {
            int col = 256 + 4 * tx + j;  // cols 256..479
            atomicAdd(&sq[col2ch(col)], ssq[4 + j]);
            ssq[4 + j] = 0.0f;
        }
    }
}

// Block handles ROWS_PER_BLOCK contiguous rows. Threads: (tx 0..63) x (ty 0..3).
// Lane tx loads float4 at col4 = tx (cols 4tx..4tx+3) and col4 = 64+tx (tx<56).
// Per-thread register accumulators for its 8 owned columns; flushed to global
// atomics only when the graph id changes (batch_id is sorted).
__global__ __launch_bounds__(256) void stats_kernel(const float* __restrict__ x,
                                                    const int* __restrict__ bid,
                                                    float* __restrict__ ws, int N) {
    const int tx = threadIdx.x & 63;
    const int ty = threadIdx.x >> 6;
    const int r0 = blockIdx.x * ROWS_PER_BLOCK;
    const int r1 = min(r0 + ROWS_PER_BLOCK, N);

    float ssq[8] = {0, 0, 0, 0, 0, 0, 0, 0};
    float ssum[4] = {0, 0, 0, 0};
    int gcur = -1;

    for (int r = r0 + ty; r < r1; r += 4) {
        int g = bid[r];
        if (g != gcur) {
            if (gcur >= 0) flush_stats(ws, gcur, tx, ssq, ssum);
            gcur = g;
        }
        const float4* rowp = (const float4*)(x + (size_t)r * DIM);
        float4 v0 = rowp[tx];
        ssq[0] += v0.x * v0.x; ssq[1] += v0.y * v0.y;
        ssq[2] += v0.z * v0.z; ssq[3] += v0.w * v0.w;
        if (tx < 32) {   // cols 4tx..4tx+3 < 128: scalar channels need plain sum too
            ssum[0] += v0.x; ssum[1] += v0.y; ssum[2] += v0.z; ssum[3] += v0.w;
        }
        if (tx < 56) {
            float4 v1 = rowp[64 + tx];
            ssq[4] += v1.x * v1.x; ssq[5] += v1.y * v1.y;
            ssq[6] += v1.z * v1.z; ssq[7] += v1.w * v1.w;
        }
    }
    if (gcur >= 0) flush_stats(ws, gcur, tx, ssq, ssum);
}

__global__ __launch_bounds__(256) void finalize_kernel(float* __restrict__ ws,
                                                       const float* __restrict__ w,
                                                       const float* __restrict__ b) {
    int idx = blockIdx.x * 256 + threadIdx.x;
    if (idx >= NGRAPHS * DIM) return;
    int g = idx / DIM;
    int col = idx % DIM;
    const int* start = (const int*)(ws + OFF_START);
    float cnt = (float)max(start[g + 1] - start[g], 1);
    int ch = col2ch(col);
    float ssq = ws[OFF_SUMSQ + (size_t)g * NCH + ch];
    float Av, Bv;
    if (col < 128) {
        float m   = ws[OFF_SUM + (size_t)g * 128 + col] / cnt;
        float var = ssq / cnt - m * m;
        float inv = 1.0f / sqrtf(var + EPS);
        Av = inv * w[ch];
        Bv = b[col] - m * Av;
    } else if (col < 320) {
        float fnm = ssq / (3.0f * cnt);
        Av = (1.0f / sqrtf(fnm + EPS)) * w[ch];
        Bv = 0.0f;
    } else {
        float fnm = ssq / (5.0f * cnt);
        Av = (1.0f / sqrtf(fnm + EPS)) * w[ch];
        Bv = 0.0f;
    }
    ws[OFF_A + idx] = Av;
    ws[OFF_B + idx] = Bv;
}

__global__ __launch_bounds__(256) void norm_kernel(const float* __restrict__ x,
                                                   const int* __restrict__ bid,
                                                   const float* __restrict__ ws,
                                                   float* __restrict__ out, int n4) {
    const float* A = ws + OFF_A;
    const float* B = ws + OFF_B;
    int stride = gridDim.x * 256;
    for (int i = blockIdx.x * 256 + threadIdx.x; i < n4; i += stride) {
        int row = i / (DIM / 4);          // 120 float4 per row
        int c4  = i % (DIM / 4);
        int g = bid[row];
        float4 xv = ((const float4*)x)[i];
        float4 av = *(const float4*)(A + (size_t)g * DIM + c4 * 4);
        float4 bv = *(const float4*)(B + (size_t)g * DIM + c4 * 4);
        float4 o;
        o.x = xv.x * av.x + bv.x;
        o.y = xv.y * av.y + bv.y;
        o.z = xv.z * av.z + bv.z;
        o.w = xv.w * av.w + bv.w;
        ((float4*)out)[i] = o;
    }
}

extern "C" void kernel_launch(void* const* d_in, const int* in_sizes, int n_in,
                              void* d_out, int out_size, void* d_ws, size_t ws_size,
                              hipStream_t stream) {
    const float* x   = (const float*)d_in[0];
    const int*   bid = (const int*)d_in[1];
    const float* w   = (const float*)d_in[2];
    const float* b   = (const float*)d_in[3];
    float* ws  = (float*)d_ws;
    float* out = (float*)d_out;
    const int N = in_sizes[1];            // 200000 rows

    // 1) zero the stats accumulators
    zero_kernel<<<(NZERO + 255) / 256, 256, 0, stream>>>(ws);
    // 2) per-graph start offsets (binary search over sorted batch_id)
    start_kernel<<<1, 128, 0, stream>>>(bid, (int*)(ws + OFF_START), N);
    // 3) accumulate per-(graph, channel) sum / sumsq
    stats_kernel<<<(N + ROWS_PER_BLOCK - 1) / ROWS_PER_BLOCK, 256, 0, stream>>>(x, bid, ws, N);
    // 4) build per-(graph, col) scale/shift tables
    finalize_kernel<<<(NGRAPHS * DIM + 255) / 256, 256, 0, stream>>>(ws, w, b);
    // 5) apply out = x*A + B
    int n4 = N * (DIM / 4);
    norm_kernel<<<2048, 256, 0, stream>>>(x, bid, ws, out, n4);
}

// Round 3
// 257.056 us; speedup vs baseline: 1.2075x; 1.2075x over previous
//
#include <hip/hip_runtime.h>

#define NGRAPHS 64
#define DIM 480            // floats per row
#define NCH 224            // 128 scalar + 64 vec3 + 32 vec5 channels
#define EPS 1e-5f
#define TILE 128           // rows per (graph-aligned) tile

typedef float f32x4 __attribute__((ext_vector_type(4)));

// ws layout (4-byte slots):
// [0, 14336)        sumsq per (g, channel)        64*224 floats
// [14336, 22528)    sum per (g, scalar channel)   64*128 floats
// [22528, 22593)    start offsets                 65 ints
// [22593, 22658)    tile prefix (tpre[64]=total)  65 ints
#define OFF_SSQ   0
#define OFF_SUM   14336
#define OFF_START 22528
#define OFF_TPRE  22593
#define ZN_FLOATS 22528    // floats to zero (sumsq + sum)

__device__ __forceinline__ int col2ch(int col) {
    if (col < 128) return col;
    if (col < 320) return 128 + (col - 128) / 3;
    return 192 + (col - 320) / 5;
}

// K1: blocks 0..87 zero the stats accumulators; block 88 computes per-graph
// start offsets (binary search over sorted batch_id) and the tile-prefix table.
__global__ __launch_bounds__(256) void init_kernel(const int* __restrict__ bid,
                                                   float* __restrict__ ws, int N) {
    int b = blockIdx.x;
    if (b < 88) {
        int i = b * 256 + threadIdx.x;
        if (i < ZN_FLOATS) ws[i] = 0.0f;
        return;
    }
    int* start = (int*)(ws + OFF_START);
    int* tpre  = (int*)(ws + OFF_TPRE);
    int g = threadIdx.x;
    if (g <= NGRAPHS) {
        int lo = 0, hi = N;                 // lower_bound: first i with bid[i] >= g
        while (lo < hi) {
            int mid = (lo + hi) >> 1;
            if (bid[mid] < g) lo = mid + 1; else hi = mid;
        }
        start[g] = lo;
    }
    __syncthreads();
    if (threadIdx.x == 0) {
        int acc = 0;
        for (int gg = 0; gg < NGRAPHS; ++gg) {
            tpre[gg] = acc;
            int cnt = start[gg + 1] - start[gg];
            acc += (cnt + TILE - 1) / TILE;
        }
        tpre[NGRAPHS] = acc;
    }
}

// map flat tile index b -> (graph, tile-within-graph). Requires b < tpre[64].
__device__ __forceinline__ void block_tile(const int* __restrict__ tpre, int b,
                                           int& g, int& tile) {
    int lo = 0, hi = NGRAPHS;          // largest g with tpre[g] <= b
    while (hi - lo > 1) {
        int mid = (lo + hi) >> 1;
        if (tpre[mid] <= b) lo = mid; else hi = mid;
    }
    g = lo;
    tile = b - tpre[lo];
}

__device__ __forceinline__ void flush_quad(float* __restrict__ SQ, int col0,
                                           float v0, float v1, float v2, float v3) {
    // combine consecutive cols sharing a channel before the atomic
    float v[4] = {v0, v1, v2, v3};
    int ch0 = col2ch(col0), ch1 = col2ch(col0 + 1),
        ch2 = col2ch(col0 + 2), ch3 = col2ch(col0 + 3);
    float acc = v[0]; int cur = ch0;
    if (ch1 == cur) acc += v[1]; else { atomicAdd(&SQ[cur], acc); cur = ch1; acc = v[1]; }
    if (ch2 == cur) acc += v[2]; else { atomicAdd(&SQ[cur], acc); cur = ch2; acc = v[2]; }
    if (ch3 == cur) acc += v[3]; else { atomicAdd(&SQ[cur], acc); cur = ch3; acc = v[3]; }
    atomicAdd(&SQ[cur], acc);
}

// K2: per-(graph,tile) block accumulates sum/sumsq. Lane tx owns cols
// 4tx..4tx+3 and 256+4tx..259+4tx (tx<56); ty = row phase. LDS-reduce across
// the 4 ty copies, then one channel-combined atomic flush per block.
__global__ __launch_bounds__(256) void stats_kernel(const float* __restrict__ x,
                                                    float* __restrict__ ws) {
    const int* start = (const int*)(ws + OFF_START);
    const int* tpre  = (const int*)(ws + OFF_TPRE);
    if ((int)blockIdx.x >= tpre[NGRAPHS]) return;
    int g, tile;
    block_tile(tpre, blockIdx.x, g, tile);
    int r0 = start[g] + tile * TILE;
    int r1 = min(r0 + TILE, start[g + 1]);

    const int tx = threadIdx.x & 63;
    const int ty = threadIdx.x >> 6;

    float ssq[8] = {0, 0, 0, 0, 0, 0, 0, 0};
    float ssum[4] = {0, 0, 0, 0};

    for (int r = r0 + ty; r < r1; r += 4) {
        const float4* rowp = (const float4*)(x + (size_t)r * DIM);
        float4 v0 = rowp[tx];
        ssq[0] += v0.x * v0.x; ssq[1] += v0.y * v0.y;
        ssq[2] += v0.z * v0.z; ssq[3] += v0.w * v0.w;
        if (tx < 32) {                       // cols < 128: scalar channels
            ssum[0] += v0.x; ssum[1] += v0.y; ssum[2] += v0.z; ssum[3] += v0.w;
        }
        if (tx < 56) {
            float4 v1 = rowp[64 + tx];
            ssq[4] += v1.x * v1.x; ssq[5] += v1.y * v1.y;
            ssq[6] += v1.z * v1.z; ssq[7] += v1.w * v1.w;
        }
    }

    __shared__ float red[256][12];           // 12 KB
#pragma unroll
    for (int j = 0; j < 8; ++j) red[threadIdx.x][j] = ssq[j];
#pragma unroll
    for (int j = 0; j < 4; ++j) red[threadIdx.x][8 + j] = ssum[j];
    __syncthreads();

    if (ty == 0) {
        float s[8], sm[4];
#pragma unroll
        for (int j = 0; j < 8; ++j)
            s[j] = red[tx][j] + red[tx + 64][j] + red[tx + 128][j] + red[tx + 192][j];
#pragma unroll
        for (int j = 0; j < 4; ++j)
            sm[j] = red[tx][8 + j] + red[tx + 64][8 + j] + red[tx + 128][8 + j] + red[tx + 192][8 + j];

        float* SQ = ws + OFF_SSQ + (size_t)g * NCH;
        float* SM = ws + OFF_SUM + (size_t)g * 128;
        flush_quad(SQ, 4 * tx, s[0], s[1], s[2], s[3]);
        if (tx < 32) {
#pragma unroll
            for (int j = 0; j < 4; ++j) atomicAdd(&SM[4 * tx + j], sm[j]);
        }
        if (tx < 56) flush_quad(SQ, 256 + 4 * tx, s[4], s[5], s[6], s[7]);
    }
}

// K3: per-(graph,tile) block, reversed order. Thread t<240: row_off=t/120,
// c4=t%120 fixed -> A/B for its 4 cols computed inline once (registers), then
// pure stream: out = x*A+B with nontemporal stores.
__global__ __launch_bounds__(256) void norm_kernel(const float* __restrict__ x,
                                                   const float* __restrict__ w,
                                                   const float* __restrict__ bias,
                                                   const float* __restrict__ ws,
                                                   float* __restrict__ out) {
    const int* start = (const int*)(ws + OFF_START);
    const int* tpre  = (const int*)(ws + OFF_TPRE);
    int total = tpre[NGRAPHS];
    int b = total - 1 - (int)blockIdx.x;     // reverse: read K2's L3-warm tail first
    if (b < 0) return;
    int t = threadIdx.x;
    if (t >= 240) return;
    int g, tile;
    block_tile(tpre, b, g, tile);
    int r0 = start[g] + tile * TILE;
    int r1 = min(r0 + TILE, start[g + 1]);

    int row_off = t / 120;                   // 0 or 1
    int c4 = t - row_off * 120;              // fixed col-quad for this thread

    float cnt = (float)max(start[g + 1] - start[g], 1);
    const float* SQ = ws + OFF_SSQ + (size_t)g * NCH;
    const float* SM = ws + OFF_SUM + (size_t)g * 128;

    float A[4], B[4];
#pragma unroll
    for (int j = 0; j < 4; ++j) {
        int col = 4 * c4 + j;
        int ch = col2ch(col);
        float ssq = SQ[ch];
        if (col < 128) {
            float m   = SM[col] / cnt;
            float var = ssq / cnt - m * m;
            float Av  = rsqrtf(var + EPS) * w[ch];
            A[j] = Av;
            B[j] = bias[col] - m * Av;
        } else {
            float d = (col < 320) ? 3.0f : 5.0f;
            A[j] = rsqrtf(ssq / (d * cnt) + EPS) * w[ch];
            B[j] = 0.0f;
        }
    }

    const float4* xp = (const float4*)(x + (size_t)(r0 + row_off) * DIM) + c4;
    float*        op = out + (size_t)(r0 + row_off) * DIM + 4 * c4;
    const int stride4 = 2 * (DIM / 4);       // 2 rows of float4s
    const int strideF = 2 * DIM;
    for (int r = r0 + row_off; r < r1; r += 2) {
        float4 xv = *xp;
        f32x4 o;
        o.x = xv.x * A[0] + B[0];
        o.y = xv.y * A[1] + B[1];
        o.z = xv.z * A[2] + B[2];
        o.w = xv.w * A[3] + B[3];
        __builtin_nontemporal_store(o, (f32x4*)op);
        xp += stride4;
        op += strideF;
    }
}

extern "C" void kernel_launch(void* const* d_in, const int* in_sizes, int n_in,
                              void* d_out, int out_size, void* d_ws, size_t ws_size,
                              hipStream_t stream) {
    const float* x   = (const float*)d_in[0];
    const int*   bid = (const int*)d_in[1];
    const float* w   = (const float*)d_in[2];
    const float* b   = (const float*)d_in[3];
    float* ws  = (float*)d_ws;
    float* out = (float*)d_out;
    const int N = in_sizes[1];

    int max_tiles = (N + TILE - 1) / TILE + NGRAPHS;   // upper bound on tpre[64]

    init_kernel<<<89, 256, 0, stream>>>(bid, ws, N);
    stats_kernel<<<max_tiles, 256, 0, stream>>>(x, ws);
    norm_kernel<<<max_tiles, 256, 0, stream>>>(x, w, b, ws, out);
}